// Round 2
// baseline (537.730 us; speedup 1.0000x reference)
//
#include <hip/hip_runtime.h>

#define N_FEAT 128
#define HID 16

// ---------------- degree: deg[v] = in-degree(v) (self-loop added later) ----
__global__ void deg_kernel(const int* __restrict__ dst,
                           float* __restrict__ deg, int E) {
    int e = blockIdx.x * blockDim.x + threadIdx.x;
    if (e < E) atomicAdd(&deg[dst[e]], 1.0f);
}

// ---------------- dinv[v] = rsqrt(deg[v] + 1)  (in place) ------------------
__global__ void dinv_kernel(float* __restrict__ deg, int n) {
    int v = blockIdx.x * blockDim.x + threadIdx.x;
    if (v < n) deg[v] = rsqrtf(deg[v] + 1.0f);
}

// ---------------- g1[v,:] = (x[v,:] @ W1) * dinv[v] ------------------------
__global__ void xform1_kernel(const float* __restrict__ x,
                              const float* __restrict__ W1,
                              const float* __restrict__ dinv,
                              float* __restrict__ g1, int n) {
    __shared__ float Ws[N_FEAT * HID];
    for (int i = threadIdx.x; i < N_FEAT * HID; i += blockDim.x)
        Ws[i] = W1[i];
    __syncthreads();

    int v = blockIdx.x * blockDim.x + threadIdx.x;
    if (v >= n) return;

    float acc[HID];
#pragma unroll
    for (int j = 0; j < HID; ++j) acc[j] = 0.0f;

    const float4* xr = (const float4*)(x + (size_t)v * N_FEAT);
#pragma unroll
    for (int k4 = 0; k4 < N_FEAT / 4; ++k4) {
        float4 xv = xr[k4];
        int k = k4 * 4;
#pragma unroll
        for (int j = 0; j < HID; ++j) {
            acc[j] += xv.x * Ws[(k + 0) * HID + j]
                    + xv.y * Ws[(k + 1) * HID + j]
                    + xv.z * Ws[(k + 2) * HID + j]
                    + xv.w * Ws[(k + 3) * HID + j];
        }
    }
    float dv = dinv[v];
    float4* out = (float4*)(g1 + (size_t)v * HID);
#pragma unroll
    for (int q = 0; q < HID / 4; ++q) {
        float4 o;
        o.x = acc[q * 4 + 0] * dv;
        o.y = acc[q * 4 + 1] * dv;
        o.z = acc[q * 4 + 2] * dv;
        o.w = acc[q * 4 + 3] * dv;
        out[q] = o;
    }
}

// ---------------- scatter-add: acc[d,:] += g[s,:] over edges ---------------
__global__ void agg_kernel(const int* __restrict__ src,
                           const int* __restrict__ dst,
                           const float* __restrict__ g,
                           float* __restrict__ acc, long long total) {
    long long i = (long long)blockIdx.x * blockDim.x + threadIdx.x;
    if (i >= total) return;
    int e = (int)(i >> 4);
    int j = (int)(i & 15);
    int s = src[e];
    int d = dst[e];
    atomicAdd(&acc[(size_t)d * HID + j], g[(size_t)s * HID + j]);
}

// ---- t = relu(dinv*(a1+g1)+b1); g2 = (t @ W2) * dinv ; g2 overwrites a1 ---
__global__ void fin1_xform2_kernel(float* __restrict__ a1,   // in: a1, out: g2
                                   const float* __restrict__ g1,
                                   const float* __restrict__ dinv,
                                   const float* __restrict__ b1,
                                   const float* __restrict__ W2,
                                   int n) {
    int v = blockIdx.x * blockDim.x + threadIdx.x;
    if (v >= n) return;
    float dv = dinv[v];

    const float4* a4 = (const float4*)(a1 + (size_t)v * HID);
    const float4* s4 = (const float4*)(g1 + (size_t)v * HID);
    float t[HID];
#pragma unroll
    for (int q = 0; q < HID / 4; ++q) {
        float4 av = a4[q];
        float4 sv = s4[q];
        t[q * 4 + 0] = fmaxf(dv * (av.x + sv.x) + b1[q * 4 + 0], 0.0f);
        t[q * 4 + 1] = fmaxf(dv * (av.y + sv.y) + b1[q * 4 + 1], 0.0f);
        t[q * 4 + 2] = fmaxf(dv * (av.z + sv.z) + b1[q * 4 + 2], 0.0f);
        t[q * 4 + 3] = fmaxf(dv * (av.w + sv.w) + b1[q * 4 + 3], 0.0f);
    }

    float4* out = (float4*)(a1 + (size_t)v * HID);   // in-place: g2 over a1
#pragma unroll
    for (int q = 0; q < HID / 4; ++q) {
        float4 o;
        float h[4];
#pragma unroll
        for (int r = 0; r < 4; ++r) {
            int j2 = q * 4 + r;
            float acc = 0.0f;
#pragma unroll
            for (int j = 0; j < HID; ++j) acc += t[j] * W2[j * HID + j2];
            h[r] = acc * dv;
        }
        o.x = h[0]; o.y = h[1]; o.z = h[2]; o.w = h[3];
        out[q] = o;
    }
}

// ---------------- out = dinv*(acc2 + g2) + b2  (acc2 == d_out, in place) ---
__global__ void fin2_kernel(float* __restrict__ out,
                            const float* __restrict__ g2,
                            const float* __restrict__ dinv,
                            const float* __restrict__ b2, int n) {
    int v = blockIdx.x * blockDim.x + threadIdx.x;
    if (v >= n) return;
    float dv = dinv[v];
    float4* o4 = (float4*)(out + (size_t)v * HID);
    const float4* g4 = (const float4*)(g2 + (size_t)v * HID);
#pragma unroll
    for (int q = 0; q < HID / 4; ++q) {
        float4 ov = o4[q];
        float4 gv = g4[q];
        float4 r;
        r.x = dv * (ov.x + gv.x) + b2[q * 4 + 0];
        r.y = dv * (ov.y + gv.y) + b2[q * 4 + 1];
        r.z = dv * (ov.z + gv.z) + b2[q * 4 + 2];
        r.w = dv * (ov.w + gv.w) + b2[q * 4 + 3];
        o4[q] = r;
    }
}

extern "C" void kernel_launch(void* const* d_in, const int* in_sizes, int n_in,
                              void* d_out, int out_size, void* d_ws, size_t ws_size,
                              hipStream_t stream) {
    const float* x  = (const float*)d_in[0];
    const int*   ei = (const int*)d_in[1];     // int32 (JAX x64 disabled)
    const float* W1 = (const float*)d_in[2];
    const float* b1 = (const float*)d_in[3];
    const float* W2 = (const float*)d_in[4];
    const float* b2 = (const float*)d_in[5];
    float* out = (float*)d_out;

    const int n = in_sizes[0] / N_FEAT;         // 100000
    const int E = in_sizes[1] / 2;              // 3200000
    const int* src = ei;
    const int* dst = ei + E;

    // workspace layout (floats), 256-aligned node count; 33*nal floats total
    size_t nal = ((size_t)n + 255) & ~(size_t)255;
    float* w    = (float*)d_ws;
    float* deg  = w;                  // nal          (becomes dinv in place)
    float* a1   = w + nal;            // 16*nal       (becomes g2 in place)
    float* g1   = a1 + 16 * nal;      // 16*nal

    // zero deg + a1 (contiguous) and d_out (layer-2 accumulator)
    hipMemsetAsync(d_ws, 0, (nal * 17) * sizeof(float), stream);
    hipMemsetAsync(d_out, 0, (size_t)out_size * sizeof(float), stream);

    const int B = 256;

    deg_kernel<<<(E + B - 1) / B, B, 0, stream>>>(dst, deg, E);
    dinv_kernel<<<(n + B - 1) / B, B, 0, stream>>>(deg, n);

    xform1_kernel<<<(n + B - 1) / B, B, 0, stream>>>(x, W1, deg, g1, n);

    long long total = (long long)E * HID;
    agg_kernel<<<(int)((total + B - 1) / B), B, 0, stream>>>(src, dst, g1, a1, total);

    fin1_xform2_kernel<<<(n + B - 1) / B, B, 0, stream>>>(a1, g1, deg, b1, W2, n);

    agg_kernel<<<(int)((total + B - 1) / B), B, 0, stream>>>(src, dst, a1, out, total);

    fin2_kernel<<<(n + B - 1) / B, B, 0, stream>>>(out, a1, deg, b2, n);
}

// Round 3
// 522.188 us; speedup vs baseline: 1.0298x; 1.0298x over previous
//
#include <hip/hip_runtime.h>

#define N_FEAT 128
#define HID 16

// ========================= shared: xform1 ==================================
// g1[v,:] = (x[v,:] @ W1) * dinv[v]
__global__ void xform1_kernel(const float* __restrict__ x,
                              const float* __restrict__ W1,
                              const float* __restrict__ dinv,
                              float* __restrict__ g1, int n) {
    __shared__ float Ws[N_FEAT * HID];
    for (int i = threadIdx.x; i < N_FEAT * HID; i += blockDim.x)
        Ws[i] = W1[i];
    __syncthreads();

    int v = blockIdx.x * blockDim.x + threadIdx.x;
    if (v >= n) return;

    float acc[HID];
#pragma unroll
    for (int j = 0; j < HID; ++j) acc[j] = 0.0f;

    const float4* xr = (const float4*)(x + (size_t)v * N_FEAT);
#pragma unroll
    for (int k4 = 0; k4 < N_FEAT / 4; ++k4) {
        float4 xv = xr[k4];
        int k = k4 * 4;
#pragma unroll
        for (int j = 0; j < HID; ++j) {
            acc[j] += xv.x * Ws[(k + 0) * HID + j]
                    + xv.y * Ws[(k + 1) * HID + j]
                    + xv.z * Ws[(k + 2) * HID + j]
                    + xv.w * Ws[(k + 3) * HID + j];
        }
    }
    float dv = dinv[v];
    float4* out = (float4*)(g1 + (size_t)v * HID);
#pragma unroll
    for (int q = 0; q < HID / 4; ++q) {
        float4 o;
        o.x = acc[q * 4 + 0] * dv;
        o.y = acc[q * 4 + 1] * dv;
        o.z = acc[q * 4 + 2] * dv;
        o.w = acc[q * 4 + 3] * dv;
        out[q] = o;
    }
}

// ========================= CSR path ========================================

// ---- histogram of dst (int) ----
__global__ void hist_kernel(const int* __restrict__ dst,
                            int* __restrict__ cnt, int E) {
    int i = blockIdx.x * blockDim.x + threadIdx.x;
    int base = i * 4;
    if (base + 3 < E) {
        int4 d = ((const int4*)dst)[i];
        atomicAdd(&cnt[d.x], 1);
        atomicAdd(&cnt[d.y], 1);
        atomicAdd(&cnt[d.z], 1);
        atomicAdd(&cnt[d.w], 1);
    } else {
        for (int e = base; e < E; ++e) atomicAdd(&cnt[dst[e]], 1);
    }
}

// ---- scan stage 1: per-block sums of cnt ----
__global__ void scan1_kernel(const int* __restrict__ cnt,
                             int* __restrict__ bsum, int n) {
    __shared__ int l[256];
    int v = blockIdx.x * 256 + threadIdx.x;
    int val = (v < n) ? cnt[v] : 0;
    l[threadIdx.x] = val;
    __syncthreads();
    for (int off = 128; off > 0; off >>= 1) {
        if (threadIdx.x < off) l[threadIdx.x] += l[threadIdx.x + off];
        __syncthreads();
    }
    if (threadIdx.x == 0) bsum[blockIdx.x] = l[0];
}

// ---- scan stage 2: exclusive scan of block sums (single block, 512 thr) ---
__global__ void scan2_kernel(int* __restrict__ bsum, int nb) {
    __shared__ int l[512];
    int t = threadIdx.x;
    int val = (t < nb) ? bsum[t] : 0;
    l[t] = val;
    __syncthreads();
    for (int off = 1; off < 512; off <<= 1) {
        int tmp = (t >= off) ? l[t - off] : 0;
        __syncthreads();
        l[t] += tmp;
        __syncthreads();
    }
    if (t < nb) bsum[t] = l[t] - val;   // exclusive
}

// ---- scan stage 3: row_start / cursor / dinv ----
__global__ void scan3_kernel(const int* __restrict__ cnt,
                             const int* __restrict__ bsum,
                             int* __restrict__ row_start,
                             int* __restrict__ cursor,
                             float* __restrict__ dinv, int n, int E) {
    __shared__ int l[256];
    int t = threadIdx.x;
    int v = blockIdx.x * 256 + t;
    int val = (v < n) ? cnt[v] : 0;
    l[t] = val;
    __syncthreads();
    for (int off = 1; off < 256; off <<= 1) {
        int tmp = (t >= off) ? l[t - off] : 0;
        __syncthreads();
        l[t] += tmp;
        __syncthreads();
    }
    if (v < n) {
        int excl = l[t] - val + bsum[blockIdx.x];
        row_start[v] = excl;
        cursor[v]    = excl;
        dinv[v]      = rsqrtf((float)val + 1.0f);
        if (v == n - 1) row_start[n] = excl + val;   // == E
    }
}

// ---- scatter: slots grouped by dst ----
__global__ void scatter_kernel(const int* __restrict__ src,
                               const int* __restrict__ dst,
                               int* __restrict__ cursor,
                               int* __restrict__ slots, int E) {
    int e = blockIdx.x * blockDim.x + threadIdx.x;
    if (e >= E) return;
    int d = dst[e];
    int pos = atomicAdd(&cursor[d], 1);
    slots[pos] = src[e];
}

// ---- layer-1 aggregation, fused finalize+relu+W2 transform ----
// per node v (16-lane group, lane = feature j):
//   acc_j = sum_{s in N(v)} g1[s][j]
//   t_j   = relu(dv*(acc_j + g1[v][j]) + b1[j])
//   g2[v][j2] = dv * sum_j t_j * W2[j][j2]
__global__ void agg1_fused_kernel(const int* __restrict__ row_start,
                                  const int* __restrict__ slots,
                                  const float* __restrict__ g1,
                                  const float* __restrict__ dinv,
                                  const float* __restrict__ b1,
                                  const float* __restrict__ W2,
                                  float* __restrict__ g2, int n) {
    __shared__ float W2s[HID * HID];
    if (threadIdx.x < HID * HID) W2s[threadIdx.x] = W2[threadIdx.x];
    __syncthreads();

    int v = blockIdx.x * 16 + (threadIdx.x >> 4);
    int j = threadIdx.x & 15;
    if (v >= n) return;

    int rs = row_start[v];
    int re = row_start[v + 1];

    float a0 = 0.f, a1 = 0.f, a2 = 0.f, a3 = 0.f;
    int k = rs;
    for (; k + 4 <= re; k += 4) {
        int s0 = slots[k], s1 = slots[k + 1], s2 = slots[k + 2], s3 = slots[k + 3];
        a0 += g1[(size_t)s0 * HID + j];
        a1 += g1[(size_t)s1 * HID + j];
        a2 += g1[(size_t)s2 * HID + j];
        a3 += g1[(size_t)s3 * HID + j];
    }
    for (; k < re; ++k) a0 += g1[(size_t)slots[k] * HID + j];
    float acc = (a0 + a1) + (a2 + a3);

    float dv = dinv[v];
    float t = fmaxf(dv * (acc + g1[(size_t)v * HID + j]) + b1[j], 0.0f);

    // 16x16 transform via width-16 shuffles
    float h = 0.0f;
#pragma unroll
    for (int jj = 0; jj < HID; ++jj) {
        float tv = __shfl(t, jj, 16);
        h += tv * W2s[jj * HID + j];
    }
    g2[(size_t)v * HID + j] = h * dv;
}

// ---- layer-2 aggregation, fused finalize+bias, writes d_out ----
__global__ void agg2_fused_kernel(const int* __restrict__ row_start,
                                  const int* __restrict__ slots,
                                  const float* __restrict__ g2,
                                  const float* __restrict__ dinv,
                                  const float* __restrict__ b2,
                                  float* __restrict__ out, int n) {
    int v = blockIdx.x * 16 + (threadIdx.x >> 4);
    int j = threadIdx.x & 15;
    if (v >= n) return;

    int rs = row_start[v];
    int re = row_start[v + 1];

    float a0 = 0.f, a1 = 0.f, a2 = 0.f, a3 = 0.f;
    int k = rs;
    for (; k + 4 <= re; k += 4) {
        int s0 = slots[k], s1 = slots[k + 1], s2 = slots[k + 2], s3 = slots[k + 3];
        a0 += g2[(size_t)s0 * HID + j];
        a1 += g2[(size_t)s1 * HID + j];
        a2 += g2[(size_t)s2 * HID + j];
        a3 += g2[(size_t)s3 * HID + j];
    }
    for (; k < re; ++k) a0 += g2[(size_t)slots[k] * HID + j];
    float acc = (a0 + a1) + (a2 + a3);

    float dv = dinv[v];
    out[(size_t)v * HID + j] = dv * (acc + g2[(size_t)v * HID + j]) + b2[j];
}

// ========================= fallback (atomic) path ==========================
__global__ void deg_kernel(const int* __restrict__ dst,
                           float* __restrict__ deg, int E) {
    int e = blockIdx.x * blockDim.x + threadIdx.x;
    if (e < E) atomicAdd(&deg[dst[e]], 1.0f);
}

__global__ void dinv_kernel(float* __restrict__ deg, int n) {
    int v = blockIdx.x * blockDim.x + threadIdx.x;
    if (v < n) deg[v] = rsqrtf(deg[v] + 1.0f);
}

__global__ void agg_kernel(const int* __restrict__ src,
                           const int* __restrict__ dst,
                           const float* __restrict__ g,
                           float* __restrict__ acc, long long total) {
    long long i = (long long)blockIdx.x * blockDim.x + threadIdx.x;
    if (i >= total) return;
    int e = (int)(i >> 4);
    int j = (int)(i & 15);
    atomicAdd(&acc[(size_t)dst[e] * HID + j], g[(size_t)src[e] * HID + j]);
}

__global__ void fin1_xform2_kernel(float* __restrict__ a1,
                                   const float* __restrict__ g1,
                                   const float* __restrict__ dinv,
                                   const float* __restrict__ b1,
                                   const float* __restrict__ W2,
                                   int n) {
    int v = blockIdx.x * blockDim.x + threadIdx.x;
    if (v >= n) return;
    float dv = dinv[v];
    const float4* a4 = (const float4*)(a1 + (size_t)v * HID);
    const float4* s4 = (const float4*)(g1 + (size_t)v * HID);
    float t[HID];
#pragma unroll
    for (int q = 0; q < HID / 4; ++q) {
        float4 av = a4[q];
        float4 sv = s4[q];
        t[q * 4 + 0] = fmaxf(dv * (av.x + sv.x) + b1[q * 4 + 0], 0.0f);
        t[q * 4 + 1] = fmaxf(dv * (av.y + sv.y) + b1[q * 4 + 1], 0.0f);
        t[q * 4 + 2] = fmaxf(dv * (av.z + sv.z) + b1[q * 4 + 2], 0.0f);
        t[q * 4 + 3] = fmaxf(dv * (av.w + sv.w) + b1[q * 4 + 3], 0.0f);
    }
    float4* outp = (float4*)(a1 + (size_t)v * HID);
#pragma unroll
    for (int q = 0; q < HID / 4; ++q) {
        float4 o;
        float h[4];
#pragma unroll
        for (int r = 0; r < 4; ++r) {
            int j2 = q * 4 + r;
            float acc = 0.0f;
#pragma unroll
            for (int j = 0; j < HID; ++j) acc += t[j] * W2[j * HID + j2];
            h[r] = acc * dv;
        }
        o.x = h[0]; o.y = h[1]; o.z = h[2]; o.w = h[3];
        outp[q] = o;
    }
}

__global__ void fin2_kernel(float* __restrict__ out,
                            const float* __restrict__ g2,
                            const float* __restrict__ dinv,
                            const float* __restrict__ b2, int n) {
    int v = blockIdx.x * blockDim.x + threadIdx.x;
    if (v >= n) return;
    float dv = dinv[v];
    float4* o4 = (float4*)(out + (size_t)v * HID);
    const float4* g4 = (const float4*)(g2 + (size_t)v * HID);
#pragma unroll
    for (int q = 0; q < HID / 4; ++q) {
        float4 ov = o4[q];
        float4 gv = g4[q];
        float4 r;
        r.x = dv * (ov.x + gv.x) + b2[q * 4 + 0];
        r.y = dv * (ov.y + gv.y) + b2[q * 4 + 1];
        r.z = dv * (ov.z + gv.z) + b2[q * 4 + 2];
        r.w = dv * (ov.w + gv.w) + b2[q * 4 + 3];
        o4[q] = r;
    }
}

// ===========================================================================
extern "C" void kernel_launch(void* const* d_in, const int* in_sizes, int n_in,
                              void* d_out, int out_size, void* d_ws, size_t ws_size,
                              hipStream_t stream) {
    const float* x  = (const float*)d_in[0];
    const int*   ei = (const int*)d_in[1];     // int32 (JAX x64 disabled)
    const float* W1 = (const float*)d_in[2];
    const float* b1 = (const float*)d_in[3];
    const float* W2 = (const float*)d_in[4];
    const float* b2 = (const float*)d_in[5];
    float* out = (float*)d_out;

    const int n = in_sizes[0] / N_FEAT;         // 100000
    const int E = in_sizes[1] / 2;              // 3200000
    const int* src = ei;
    const int* dst = ei + E;

    const int B = 256;
    size_t nal = ((size_t)n + 255) & ~(size_t)255;

    // CSR-path workspace: cnt | row_start | cursor | bsum | slots | g1 | g2
    size_t need = (35 * nal + 768 + (size_t)E) * sizeof(float);

    if (ws_size >= need) {
        int*   cnt       = (int*)d_ws;                    // nal
        int*   row_start = cnt + nal;                     // nal + 256
        int*   cursor    = row_start + nal + 256;         // nal
        int*   bsum      = cursor + nal;                  // 512
        int*   slots     = bsum + 512;                    // E
        float* dinv      = (float*)(slots + E);           // reuse? no — separate:
        // place dinv right after slots; g1, g2 after
        float* g1        = dinv + nal;                    // 16*nal
        float* g2        = g1 + 16 * nal;                 // 16*nal

        hipMemsetAsync(cnt, 0, nal * sizeof(int), stream);

        int nb = (int)((n + 255) / 256);
        hist_kernel<<<(E / 4 + B - 1) / B, B, 0, stream>>>(dst, cnt, E);
        scan1_kernel<<<nb, 256, 0, stream>>>(cnt, bsum, n);
        scan2_kernel<<<1, 512, 0, stream>>>(bsum, nb);
        scan3_kernel<<<nb, 256, 0, stream>>>(cnt, bsum, row_start, cursor, dinv, n, E);
        scatter_kernel<<<(E + B - 1) / B, B, 0, stream>>>(src, dst, cursor, slots, E);

        xform1_kernel<<<(n + B - 1) / B, B, 0, stream>>>(x, W1, dinv, g1, n);

        int aggBlocks = (n + 15) / 16;
        agg1_fused_kernel<<<aggBlocks, 256, 0, stream>>>(row_start, slots, g1,
                                                         dinv, b1, W2, g2, n);
        agg2_fused_kernel<<<aggBlocks, 256, 0, stream>>>(row_start, slots, g2,
                                                         dinv, b2, out, n);
    } else {
        // fallback: proven atomic path
        float* w   = (float*)d_ws;
        float* deg = w;                  // nal  (becomes dinv)
        float* a1  = w + nal;            // 16*nal (becomes g2)
        float* g1  = a1 + 16 * nal;      // 16*nal

        hipMemsetAsync(d_ws, 0, (nal * 17) * sizeof(float), stream);
        hipMemsetAsync(d_out, 0, (size_t)out_size * sizeof(float), stream);

        deg_kernel<<<(E + B - 1) / B, B, 0, stream>>>(dst, deg, E);
        dinv_kernel<<<(n + B - 1) / B, B, 0, stream>>>(deg, n);
        xform1_kernel<<<(n + B - 1) / B, B, 0, stream>>>(x, W1, deg, g1, n);
        long long total = (long long)E * HID;
        agg_kernel<<<(int)((total + B - 1) / B), B, 0, stream>>>(src, dst, g1, a1, total);
        fin1_xform2_kernel<<<(n + B - 1) / B, B, 0, stream>>>(a1, g1, deg, b1, W2, n);
        agg_kernel<<<(int)((total + B - 1) / B), B, 0, stream>>>(src, dst, a1, out, total);
        fin2_kernel<<<(n + B - 1) / B, B, 0, stream>>>(out, a1, deg, b2, n);
    }
}